// Round 1
// baseline (3065.896 us; speedup 1.0000x reference)
//
#include <hip/hip_runtime.h>
#include <stdint.h>

typedef unsigned short u16;
typedef _Float16 f16x8 __attribute__((ext_vector_type(8)));
typedef float f32x4 __attribute__((ext_vector_type(4)));

#define B_ROWS 8192
#define K_DIM  4096
#define H_DIM  8192
#define W_SCALE 64.0f
#define INV_W_SCALE 0.015625f

// array strides within the contiguous ws region (u16 elements)
#define ARR_STRIDE (33554432u)   // 8192*4096

// ---------- f16 helpers ----------
__device__ __forceinline__ u16 f2h_bits(float f) {
  _Float16 h = (_Float16)f;
  return __builtin_bit_cast(u16, h);
}
__device__ __forceinline__ float h2f(u16 u) {
  return (float)__builtin_bit_cast(_Float16, u);
}

// ---------- direct global->LDS (width 16) ----------
typedef __attribute__((address_space(1))) void gvoid_t;
typedef __attribute__((address_space(3))) void lvoid_t;
#define GLOAD_LDS16(gp, lp) \
  __builtin_amdgcn_global_load_lds((gvoid_t*)(gp), (lvoid_t*)(lp), 16, 0, 0)

// ---------- x: fp32 -> f16 hi + f16 lo ----------
__global__ void split_x_kernel(const float4* __restrict__ x,
                               ushort4* __restrict__ hi,
                               ushort4* __restrict__ lo, int n4) {
  int i = blockIdx.x * blockDim.x + threadIdx.x;
  if (i >= n4) return;
  float4 v = x[i];
  ushort4 h, l;
  h.x = f2h_bits(v.x); l.x = f2h_bits(v.x - h2f(h.x));
  h.y = f2h_bits(v.y); l.y = f2h_bits(v.y - h2f(h.y));
  h.z = f2h_bits(v.z); l.z = f2h_bits(v.z - h2f(h.z));
  h.w = f2h_bits(v.w); l.w = f2h_bits(v.w - h2f(h.w));
  hi[i] = h; lo[i] = l;
}

// ---------- w1 [D,H] fp32 -> w1T [H,D] f16 hi (+lo), scaled by 64 ----------
__global__ void transpose_split_kernel(const float* __restrict__ w,
                                       u16* __restrict__ hi, u16* __restrict__ lo,
                                       int rows, int cols) {
  __shared__ float tile[32][33];
  int c0 = blockIdx.x * 32, r0 = blockIdx.y * 32;
  int tx = threadIdx.x, ty = threadIdx.y;
  #pragma unroll
  for (int j = 0; j < 4; ++j)
    tile[ty + j*8][tx] = w[(size_t)(r0 + ty + j*8) * cols + c0 + tx];
  __syncthreads();
  #pragma unroll
  for (int j = 0; j < 4; ++j) {
    int oc = c0 + ty + j*8;
    float v = tile[tx][ty + j*8] * W_SCALE;
    u16 h = f2h_bits(v);
    size_t oidx = (size_t)oc * rows + r0 + tx;
    hi[oidx] = h;
    if (lo) lo[oidx] = f2h_bits(v - h2f(h));
  }
}

// ---------- init logit accumulators with b2 ----------
__global__ void init_parts_kernel(float* __restrict__ tp, float* __restrict__ fp,
                                  const float* __restrict__ tb2,
                                  const float* __restrict__ fb2) {
  int i = blockIdx.x * blockDim.x + threadIdx.x;
  if (i < 2 * B_ROWS) { tp[i] = tb2[i & 1]; fp[i] = fb2[i & 1]; }
}

// ---------- fused layer-2 epilogue helper ----------
// C/D layout (16x16x32): col(n) = lane&15 = r, row(m) = q*4 + reg
__device__ __forceinline__ void epilogue(
    const f32x4 (&acc)[4][4], const float* __restrict__ b1,
    const float* __restrict__ w2, float* __restrict__ part,
    int mbase, int nbase, int r)
{
  float b1v[4], w20[4], w21[4];
  #pragma unroll
  for (int t = 0; t < 4; ++t) {
    int n = nbase + t * 16;
    b1v[t] = b1[n];
    w20[t] = w2[2*n];
    w21[t] = w2[2*n + 1];
  }
  #pragma unroll
  for (int tm = 0; tm < 4; ++tm) {
    #pragma unroll
    for (int v = 0; v < 4; ++v) {
      float s0 = 0.f, s1 = 0.f;
      #pragma unroll
      for (int tn = 0; tn < 4; ++tn) {
        float h = fmaxf(fmaf(acc[tm][tn][v], INV_W_SCALE, b1v[tn]), 0.f);
        s0 = fmaf(h, w20[tn], s0);
        s1 = fmaf(h, w21[tn], s1);
      }
      #pragma unroll
      for (int off = 1; off < 16; off <<= 1) {
        s0 += __shfl_xor(s0, off, 64);
        s1 += __shfl_xor(s1, off, 64);
      }
      if (r == 0) {
        int m = mbase + tm * 16 + v;
        atomicAdd(&part[2*m],     s0);
        atomicAdd(&part[2*m + 1], s1);
      }
    }
  }
}

// ---------- fused 4-pass MLP GEMM: 256x128 tile, 8 waves, dbuf BK=32 ----------
// acc_t = xh@twh^T + xl@twh^T + xh@twl^T ; acc_f = xh@fwh^T
// ws layout (u16, contiguous): xh | xl | twh | twl | fwh   (ARR_STRIDE each)
// LDS per buffer (u16 idx): xh[0,8192) xl[8192,16384) twh[16384,20480)
//                           twl[20480,24576) fwh[24576,28672)   (56 KB)
//
// K-loop schedule (T3+T4+T5): 4 phases per BK=32 slice, each
//   {ds_read fragment; s_barrier; setprio(1); 16 MFMA; setprio(0); s_barrier}
// Prefetch for slice kk+2 issued at the tail of iter kk into buf[kk&1];
// publish via counted s_waitcnt vmcnt(7) (slice kk+1's 7 loads are the
// oldest) + raw s_barrier. vmcnt never drains to 0 in steady state.
#define LBUF 28672
#define NK   (K_DIM / 32)
__global__ __launch_bounds__(512, 2) void fused_mlp_kernel(
    const u16* __restrict__ ws16,
    const float* __restrict__ tb1, const float* __restrict__ tw2,
    const float* __restrict__ fb1, const float* __restrict__ fw2,
    float* __restrict__ tp, float* __restrict__ fp)
{
  __shared__ __align__(16) u16 lds[2 * LBUF];   // 112 KB

  const int tid  = threadIdx.x;
  const int lane = tid & 63;
  const int wave = tid >> 6;          // 0..7
  const int wm = wave >> 1;           // 0..3 (m)
  const int wn = wave & 1;            // 0..1 (n)
  const int q  = lane >> 4;
  const int r  = lane & 15;

  // XCD-compact swizzle: grid 2048 = 32 bm x 64 bn. xcd = L&7 owns bn-stripe
  // [8*xcd, 8*xcd+8); the 32 co-resident blocks per XCD form a 4bm x 8bn patch.
  const int L  = blockIdx.x;
  const int s  = L >> 3;                          // 0..255
  const int bm = (s >> 5) * 4 + ((s >> 3) & 3);   // 0..31
  const int bn = (L & 7) * 8 + (s & 7);           // 0..63

  // ---- staging plan: 56 groups/iter (xh 16, xl 16, twh 8, twl 8, fwh 8),
  // 7 per wave. Group g of a tile: lane l=q*16+r holds row g*16+r, k=q*8..q*8+7
  unsigned goff[7];
  int loff[7];
  #pragma unroll
  for (int j = 0; j < 7; ++j) {
    int gid = wave * 7 + j;           // wave-uniform branches below
    unsigned arr; int g, lbase; bool isA;
    if (gid < 16)      { arr = 0; g = gid;      lbase = 0;     isA = true;  }
    else if (gid < 32) { arr = 1; g = gid - 16; lbase = 8192;  isA = true;  }
    else if (gid < 40) { arr = 2; g = gid - 32; lbase = 16384; isA = false; }
    else if (gid < 48) { arr = 3; g = gid - 40; lbase = 20480; isA = false; }
    else               { arr = 4; g = gid - 48; lbase = 24576; isA = false; }
    unsigned row = (isA ? (unsigned)bm * 256u : (unsigned)bn * 128u) + g * 16 + r;
    goff[j] = arr * ARR_STRIDE + row * (unsigned)K_DIM + q * 8;
    loff[j] = lbase + g * 512;
  }

  f32x4 at[4][4], af[4][4];
  #pragma unroll
  for (int i = 0; i < 4; ++i)
    #pragma unroll
    for (int j = 0; j < 4; ++j) {
      at[i][j] = (f32x4){0.f, 0.f, 0.f, 0.f};
      af[i][j] = (f32x4){0.f, 0.f, 0.f, 0.f};
    }

  // prologue: stage slice 0 -> buf0, slice 1 -> buf1; publish slice 0
  #pragma unroll
  for (int j = 0; j < 7; ++j)
    GLOAD_LDS16(ws16 + goff[j], &lds[loff[j]]);
  #pragma unroll
  for (int j = 0; j < 7; ++j)
    GLOAD_LDS16(ws16 + goff[j] + 32u, &lds[LBUF + loff[j]]);
  asm volatile("s_waitcnt vmcnt(7)" ::: "memory");
  __builtin_amdgcn_s_barrier();
  __builtin_amdgcn_sched_barrier(0);

  for (int kk = 0; kk < NK; ++kk) {
    const int base = (kk & 1) * LBUF;
    f16x8 ah[4], bb[4], tmp[4];

    // ---- phase 1: at += xh @ twh^T ----
    #pragma unroll
    for (int t = 0; t < 4; ++t) {
      ah[t] = *reinterpret_cast<const f16x8*>(&lds[base + (wm*4 + t)*512 + lane*8]);           // xh
      bb[t] = *reinterpret_cast<const f16x8*>(&lds[base + 16384 + (wn*4 + t)*512 + lane*8]);   // twh
    }
    __builtin_amdgcn_s_barrier();
    __builtin_amdgcn_sched_barrier(0);
    __builtin_amdgcn_s_setprio(1);
    #pragma unroll
    for (int tm = 0; tm < 4; ++tm)
      #pragma unroll
      for (int tn = 0; tn < 4; ++tn)
        at[tm][tn] = __builtin_amdgcn_mfma_f32_16x16x32_f16(ah[tm], bb[tn], at[tm][tn], 0, 0, 0);
    __builtin_amdgcn_s_setprio(0);
    __builtin_amdgcn_s_barrier();
    __builtin_amdgcn_sched_barrier(0);

    // ---- phase 2: at += xl @ twh^T ----
    #pragma unroll
    for (int t = 0; t < 4; ++t)
      tmp[t] = *reinterpret_cast<const f16x8*>(&lds[base + 8192 + (wm*4 + t)*512 + lane*8]);   // xl
    __builtin_amdgcn_s_barrier();
    __builtin_amdgcn_sched_barrier(0);
    __builtin_amdgcn_s_setprio(1);
    #pragma unroll
    for (int tm = 0; tm < 4; ++tm)
      #pragma unroll
      for (int tn = 0; tn < 4; ++tn)
        at[tm][tn] = __builtin_amdgcn_mfma_f32_16x16x32_f16(tmp[tm], bb[tn], at[tm][tn], 0, 0, 0);
    __builtin_amdgcn_s_setprio(0);
    __builtin_amdgcn_s_barrier();
    __builtin_amdgcn_sched_barrier(0);

    // ---- phase 3: at += xh @ twl^T ----
    #pragma unroll
    for (int t = 0; t < 4; ++t)
      tmp[t] = *reinterpret_cast<const f16x8*>(&lds[base + 20480 + (wn*4 + t)*512 + lane*8]);  // twl
    __builtin_amdgcn_s_barrier();
    __builtin_amdgcn_sched_barrier(0);
    __builtin_amdgcn_s_setprio(1);
    #pragma unroll
    for (int tm = 0; tm < 4; ++tm)
      #pragma unroll
      for (int tn = 0; tn < 4; ++tn)
        at[tm][tn] = __builtin_amdgcn_mfma_f32_16x16x32_f16(ah[tm], tmp[tn], at[tm][tn], 0, 0, 0);
    __builtin_amdgcn_s_setprio(0);
    __builtin_amdgcn_s_barrier();
    __builtin_amdgcn_sched_barrier(0);

    // ---- phase 4: af += xh @ fwh^T ----
    #pragma unroll
    for (int t = 0; t < 4; ++t)
      tmp[t] = *reinterpret_cast<const f16x8*>(&lds[base + 24576 + (wn*4 + t)*512 + lane*8]);  // fwh
    __builtin_amdgcn_s_barrier();
    __builtin_amdgcn_sched_barrier(0);
    __builtin_amdgcn_s_setprio(1);
    #pragma unroll
    for (int tm = 0; tm < 4; ++tm)
      #pragma unroll
      for (int tn = 0; tn < 4; ++tn)
        af[tm][tn] = __builtin_amdgcn_mfma_f32_16x16x32_f16(ah[tm], tmp[tn], af[tm][tn], 0, 0, 0);
    __builtin_amdgcn_s_setprio(0);

    // ---- tail: prefetch slice kk+2 into buf[kk&1]; publish slice kk+1.
    // Safe: every wave drained its own lgkm before its ph4 MFMAs, and the
    // gload's LDS write lands >=300cy after issue (template-verified pattern).
    if (kk + 2 < NK) {
      const unsigned ka = (unsigned)(kk + 2) * 32u;
      const int lb = (kk & 1) * LBUF;
      #pragma unroll
      for (int j = 0; j < 7; ++j)
        GLOAD_LDS16(ws16 + goff[j] + ka, &lds[lb + loff[j]]);
      asm volatile("s_waitcnt vmcnt(7)" ::: "memory");   // drain slice kk+1 only
      __builtin_amdgcn_s_barrier();
      __builtin_amdgcn_sched_barrier(0);
    } else if (kk + 1 < NK) {
      asm volatile("s_waitcnt vmcnt(0)" ::: "memory");   // last publish
      __builtin_amdgcn_s_barrier();
      __builtin_amdgcn_sched_barrier(0);
    }
  }

  const int mbase = bm * 256 + wm * 64 + q * 4;
  const int nbase = bn * 128 + wn * 64 + r;
  epilogue(at, tb1, tw2, tp, mbase, nbase, r);
  epilogue(af, fb1, fw2, fp, mbase, nbase, r);
}

// ---------- confidence select ----------
__global__ void select_kernel(const float* __restrict__ tp, const float* __restrict__ fp,
                              float* __restrict__ out) {
  int m = blockIdx.x * blockDim.x + threadIdx.x;
  if (m >= B_ROWS) return;
  float a = tp[2*m], b = tp[2*m + 1];
  float conf = 1.0f / (1.0f + expf(-fabsf(a - b)));  // max softmax prob, C=2
  bool low = conf < 0.8f;
  out[2*m]     = low ? fp[2*m]     : a;
  out[2*m + 1] = low ? fp[2*m + 1] : b;
}

extern "C" void kernel_launch(void* const* d_in, const int* in_sizes, int n_in,
                              void* d_out, int out_size, void* d_ws, size_t ws_size,
                              hipStream_t stream) {
  const float* x    = (const float*)d_in[0];
  const float* t_w1 = (const float*)d_in[1];
  const float* t_b1 = (const float*)d_in[2];
  const float* t_w2 = (const float*)d_in[3];
  const float* t_b2 = (const float*)d_in[4];
  const float* f_w1 = (const float*)d_in[5];
  const float* f_b1 = (const float*)d_in[6];
  const float* f_w2 = (const float*)d_in[7];
  const float* f_b2 = (const float*)d_in[8];
  float* out = (float*)d_out;

  const size_t SZ = (size_t)B_ROWS * K_DIM * sizeof(u16);   // 64 MB
  const size_t NEED = 5 * SZ + 2 * (size_t)(2 * B_ROWS) * sizeof(float);
  if (ws_size < NEED) return;

  char* ws = (char*)d_ws;
  u16* x_hi   = (u16*)(ws);
  u16* x_lo   = (u16*)(ws + SZ);
  u16* twT_hi = (u16*)(ws + 2 * SZ);
  u16* twT_lo = (u16*)(ws + 3 * SZ);
  u16* fwT_hi = (u16*)(ws + 4 * SZ);
  float* t_part = (float*)(ws + 5 * SZ);
  float* f_part = t_part + 2 * B_ROWS;

  split_x_kernel<<<(B_ROWS * K_DIM / 4 + 255) / 256, 256, 0, stream>>>(
      (const float4*)x, (ushort4*)x_hi, (ushort4*)x_lo, B_ROWS * K_DIM / 4);
  dim3 tb(32, 8);
  transpose_split_kernel<<<dim3(H_DIM / 32, K_DIM / 32), tb, 0, stream>>>(
      t_w1, twT_hi, twT_lo, K_DIM, H_DIM);
  transpose_split_kernel<<<dim3(H_DIM / 32, K_DIM / 32), tb, 0, stream>>>(
      f_w1, fwT_hi, nullptr, K_DIM, H_DIM);
  init_parts_kernel<<<(2 * B_ROWS + 255) / 256, 256, 0, stream>>>(
      t_part, f_part, t_b2, f_b2);

  fused_mlp_kernel<<<(B_ROWS / 256) * (H_DIM / 128), 512, 0, stream>>>(
      x_hi, t_b1, t_w2, f_b1, f_w2, t_part, f_part);

  select_kernel<<<(B_ROWS + 255) / 256, 256, 0, stream>>>(t_part, f_part, out);
}